// Round 1
// 628.051 us; speedup vs baseline: 1.2903x; 1.2903x over previous
//
#include <hip/hip_runtime.h>
#include <hip/hip_bf16.h>

typedef _Float16 half8 __attribute__((ext_vector_type(8)));
typedef float f32x4 __attribute__((ext_vector_type(4)));

#define SS 200
#define HH 128
#define NHD 4
#define FH 512
#define NTILES 32   // FH/16
#define NEGF (-4294967295.0f)

// ---------------- pre-kernel: W1 [128][512] f32 -> fp16, MFMA-B-fragment-linear ----------------
// element ((nt*4 + ks)*64 + lane)*8 + j  holds  W1[ks*32 + (lane>>4)*8 + j][nt*16 + (lane&15)]
__global__ void swizzle_w1(const float* __restrict__ W1, _Float16* __restrict__ dst) {
    int tid = blockIdx.x * blockDim.x + threadIdx.x;   // 0..65535
    int j    = tid & 7;
    int lane = (tid >> 3) & 63;
    int ks   = (tid >> 9) & 3;
    int nt   = tid >> 11;
    int k = ks * 32 + (lane >> 4) * 8 + j;
    int n = nt * 16 + (lane & 15);
    dst[tid] = (_Float16)W1[k * FH + n];
}

__device__ __forceinline__ float tanh_fast(float x) {
    x = fminf(fmaxf(x, -15.0f), 15.0f);
    float e = __expf(x + x);
    return (e - 1.0f) * __builtin_amdgcn_rcpf(e + 1.0f);
}

__device__ __forceinline__ f32x4 mfma16(half8 a, half8 b, f32x4 c) {
    return __builtin_amdgcn_mfma_f32_16x16x32_f16(a, b, c, 0, 0, 0);
}

// one group of NT m-tiles, this wave's 8 n-tiles; layout-agnostic via rowslot/colslot
// w1p may point to LDS (fallback) or global pre-swizzled workspace (fast path)
template<int NT>
__device__ __forceinline__ void process_group(
    int mstart, const float* __restrict__ xb, const float* __restrict__ pos,
    const half8* w1p, const float4* w2s, float* attw,
    int wave, int lane, int q, int c,
    const int* rowslot, const int* colslot, int path)
{
    // --- A fragments: x+pos -> fp16; slot c carries sequence row (mstart+t)*16 + c ---
    half8 af[NT][4];
#pragma unroll
    for (int t = 0; t < NT; ++t) {
        int row = (mstart + t) * 16 + c;
        bool ok = row < SS;
        const float4* xr = (const float4*)(xb + row * HH);
        const float4* pr = (const float4*)(pos + row * HH);
#pragma unroll
        for (int ks = 0; ks < 4; ++ks) {
            int ci = ks * 8 + q * 2;
            float4 x0, x1, p0, p1;
            if (ok) { x0 = xr[ci]; x1 = xr[ci + 1]; p0 = pr[ci]; p1 = pr[ci + 1]; }
            else {
                x0 = make_float4(0.f,0.f,0.f,0.f); x1 = x0; p0 = x0; p1 = x0;
            }
            half8 h;
            h[0] = (_Float16)(x0.x + p0.x); h[1] = (_Float16)(x0.y + p0.y);
            h[2] = (_Float16)(x0.z + p0.z); h[3] = (_Float16)(x0.w + p0.w);
            h[4] = (_Float16)(x1.x + p1.x); h[5] = (_Float16)(x1.y + p1.y);
            h[6] = (_Float16)(x1.z + p1.z); h[7] = (_Float16)(x1.w + p1.w);
            af[t][ks] = h;
        }
    }

    float attp[NT][4][NHD];
#pragma unroll
    for (int t = 0; t < NT; ++t)
#pragma unroll
        for (int r = 0; r < 4; ++r)
#pragma unroll
            for (int k = 0; k < NHD; ++k) attp[t][r][k] = 0.0f;

    int nt0 = wave * 8;
    for (int nt = nt0; nt < nt0 + 8; ++nt) {
        float4 w2v[4];
#pragma unroll
        for (int r = 0; r < 4; ++r) w2v[r] = w2s[nt * 16 + colslot[r]];
        half8 bf[4];
#pragma unroll
        for (int ks = 0; ks < 4; ++ks) bf[ks] = w1p[(nt * 4 + ks) * 64 + lane];
        f32x4 acc[NT];
#pragma unroll
        for (int t = 0; t < NT; ++t) { f32x4 z = {0.f,0.f,0.f,0.f}; acc[t] = z; }
#pragma unroll
        for (int ks = 0; ks < 4; ++ks)
#pragma unroll
            for (int t = 0; t < NT; ++t)
                acc[t] = mfma16(af[t][ks], bf[ks], acc[t]);
        // element (r,lane) holds hidden[(mstart+t)*16+rowslot[r]][nt*16+colslot[r]]
#pragma unroll
        for (int t = 0; t < NT; ++t)
#pragma unroll
            for (int r = 0; r < 4; ++r) {
                float h = tanh_fast(acc[t][r]);
                attp[t][r][0] += h * w2v[r].x;
                attp[t][r][1] += h * w2v[r].y;
                attp[t][r][2] += h * w2v[r].z;
                attp[t][r][3] += h * w2v[r].w;
            }
    }

    if (path == 0) {
        // guide map: rowslot[r]=q*4+r, colslot[r]=c — sum the 16 c-slots via xor 1,2,4,8
#pragma unroll
        for (int t = 0; t < NT; ++t)
#pragma unroll
            for (int r = 0; r < 4; ++r)
#pragma unroll
                for (int k = 0; k < NHD; ++k) {
                    float v = attp[t][r][k];
                    v += __shfl_xor(v, 1);
                    v += __shfl_xor(v, 2);
                    v += __shfl_xor(v, 4);
                    v += __shfl_xor(v, 8);
                    if (c == 0)
                        atomicAdd(&attw[((mstart + t) * 16 + rowslot[r]) * NHD + k], v);
                }
    } else if (path == 1) {
        // swapped map: rowslot[r]=c, colslot[r]=q*4+r — sum r locally, xor 16,32 over q
#pragma unroll
        for (int t = 0; t < NT; ++t)
#pragma unroll
            for (int k = 0; k < NHD; ++k) {
                float v = attp[t][0][k] + attp[t][1][k] + attp[t][2][k] + attp[t][3][k];
                v += __shfl_xor(v, 16);
                v += __shfl_xor(v, 32);
                if (q == 0)
                    atomicAdd(&attw[((mstart + t) * 16 + c) * NHD + k], v);
            }
    } else {
        // generic fallback: per-lane atomics, correct for any bijective map
#pragma unroll
        for (int t = 0; t < NT; ++t)
#pragma unroll
            for (int r = 0; r < 4; ++r)
#pragma unroll
                for (int k = 0; k < NHD; ++k)
                    atomicAdd(&attw[((mstart + t) * 16 + rowslot[r]) * NHD + k],
                              attp[t][r][k]);
    }
}

// USE_WS=1: W1 fragments loaded straight from global pre-swizzled workspace (L2-resident,
//           131 KiB LDS freed -> 3 blocks/CU instead of 1). USE_WS=0: old LDS-staging path.
template<int USE_WS>
__global__ __launch_bounds__(256, USE_WS ? 3 : 1)
void mhan_main(const float* __restrict__ item, const int* __restrict__ mask,
               const float* __restrict__ pos, const float* __restrict__ W1,
               const float* __restrict__ W2, const _Float16* __restrict__ w1sw,
               float* __restrict__ out)
{
    __shared__ half8  w1s_lds[USE_WS ? 1 : (NTILES * 4 * 64)];  // 131072 B only in fallback
    __shared__ float4 w2s[FH];                // 8192 B
    __shared__ float  attw[208 * NHD];        // 3328 B

    int tid = threadIdx.x;
    int b   = blockIdx.x;
    int lane = tid & 63, wave = tid >> 6;
    int q = lane >> 4, c = lane & 15;

    // ---- layout probe: 2 exact MFMAs reveal each C element's true (row,col) source slots ----
    int rowslot[4], colslot[4];
    {
        half8 pc_, pone;
#pragma unroll
        for (int j = 0; j < 8; ++j) { pc_[j] = (_Float16)(float)c; pone[j] = (_Float16)0.03125f; }
        f32x4 z = {0.f,0.f,0.f,0.f};
        f32x4 pr = mfma16(pc_, pone, z);   // value = source A-slot (row provenance)
        f32x4 pcv = mfma16(pone, pc_, z);  // value = source B-slot (col provenance)
#pragma unroll
        for (int r = 0; r < 4; ++r) {
            int rv = (int)(pr[r] + 0.5f);
            int cv = (int)(pcv[r] + 0.5f);
            rowslot[r] = rv < 0 ? 0 : (rv > 15 ? 15 : rv);
            colslot[r] = cv < 0 ? 0 : (cv > 15 ? 15 : cv);
        }
    }
    int okA = 1, okB = 1;
#pragma unroll
    for (int r = 0; r < 4; ++r) {
        okA &= (rowslot[r] == q * 4 + r) & (colslot[r] == c);
        okB &= (rowslot[r] == c) & (colslot[r] == q * 4 + r);
    }
    int path = __all(okA) ? 0 : (__all(okB) ? 1 : 2);

    // ---- stage W2, zero att; (fallback only: stage W1 into LDS) ----
    if constexpr (!USE_WS) {
        _Float16* w1f = (_Float16*)w1s_lds;
        for (int idx = tid; idx < HH * FH; idx += 256) {
            int j = idx & 7; int ln = (idx >> 3) & 63;
            int ks = (idx >> 9) & 3; int nt = idx >> 11;
            int k = ks * 32 + (ln >> 4) * 8 + j;
            int n = nt * 16 + (ln & 15);
            w1f[idx] = (_Float16)W1[k * FH + n];
        }
    }
    for (int i = tid; i < FH; i += 256) w2s[i] = ((const float4*)W2)[i];
    for (int i = tid; i < 208 * NHD; i += 256) attw[i] = 0.0f;
    __syncthreads();

    const half8* w1p;
    if constexpr (USE_WS) w1p = (const half8*)w1sw;
    else                  w1p = w1s_lds;

    const float* xb = item + (size_t)b * SS * HH;

    process_group<4>(0,  xb, pos, w1p, w2s, attw, wave, lane, q, c, rowslot, colslot, path);
    process_group<3>(4,  xb, pos, w1p, w2s, attw, wave, lane, q, c, rowslot, colslot, path);
    process_group<3>(7,  xb, pos, w1p, w2s, attw, wave, lane, q, c, rowslot, colslot, path);
    process_group<3>(10, xb, pos, w1p, w2s, attw, wave, lane, q, c, rowslot, colslot, path);
    __syncthreads();

    // ---- masked softmax over S; head k = wave ----
    {
        int k = wave;
        float l[4];
        float m = -__builtin_inff();
#pragma unroll
        for (int i = 0; i < 4; ++i) {
            int s = lane + i * 64;
            if (s < SS) {
                float lv = (mask[(size_t)b * SS + s] != 0) ? attw[s * NHD + k] : NEGF;
                l[i] = lv;
                m = fmaxf(m, lv);
            } else {
                l[i] = -__builtin_inff();
            }
        }
#pragma unroll
        for (int off = 32; off >= 1; off >>= 1) m = fmaxf(m, __shfl_xor(m, off));
        float e[4], sum = 0.0f;
#pragma unroll
        for (int i = 0; i < 4; ++i) {
            e[i] = (l[i] == -__builtin_inff()) ? 0.0f : __expf(l[i] - m);
            sum += e[i];
        }
#pragma unroll
        for (int off = 32; off >= 1; off >>= 1) sum += __shfl_xor(sum, off);
        float inv = __builtin_amdgcn_rcpf(sum);
#pragma unroll
        for (int i = 0; i < 4; ++i) {
            int s = lane + i * 64;
            if (s < SS) attw[s * NHD + k] = e[i] * inv;
        }
    }
    // wave k wrote only column k; wave k reads only column k below — same-wave DS order suffices

    // ---- interest[k][h] = sum_s w[s,k] * x[s,h]  (fp32 out — reference output is float32) ----
    {
        int k = wave;
        float ax = 0.0f, ay = 0.0f;
#pragma unroll 8
        for (int s = 0; s < SS; ++s) {
            float w = attw[s * NHD + k];
            float2 xv = ((const float2*)(xb + s * HH))[lane];
            ax += w * xv.x;
            ay += w * xv.y;
        }
        size_t o = ((size_t)b * NHD + k) * HH + lane * 2;
        float2 ov; ov.x = ax; ov.y = ay;
        *(float2*)(out + o) = ov;
    }
}

extern "C" void kernel_launch(void* const* d_in, const int* in_sizes, int n_in,
                              void* d_out, int out_size, void* d_ws, size_t ws_size,
                              hipStream_t stream) {
    const float* item = (const float*)d_in[0];
    const int*   mask = (const int*)d_in[1];
    const float* pos  = (const float*)d_in[2];
    const float* W1   = (const float*)d_in[3];
    const float* W2   = (const float*)d_in[4];
    float* out = (float*)d_out;

    int B = in_sizes[0] / (SS * HH);
    int use_ws = (ws_size >= (size_t)(HH * FH * sizeof(_Float16))) ? 1 : 0;

    if (use_ws) {
        hipLaunchKernelGGL(swizzle_w1, dim3((HH * FH) / 256), dim3(256), 0, stream,
                           W1, (_Float16*)d_ws);
        mhan_main<1><<<dim3(B), dim3(256), 0, stream>>>(
            item, mask, pos, W1, W2, (const _Float16*)d_ws, out);
    } else {
        mhan_main<0><<<dim3(B), dim3(256), 0, stream>>>(
            item, mask, pos, W1, W2, (const _Float16*)nullptr, out);
    }
}

// Round 2
// 611.152 us; speedup vs baseline: 1.3260x; 1.0277x over previous
//
#include <hip/hip_runtime.h>
#include <hip/hip_bf16.h>

typedef _Float16 half8 __attribute__((ext_vector_type(8)));
typedef float f32x4 __attribute__((ext_vector_type(4)));

#define SS 200
#define HH 128
#define NHD 4
#define FH 512
#define NTILES 32   // FH/16
#define MTILES 13   // ceil(SS/16)
#define NEGF (-4294967295.0f)

// ---------------- pre-kernel: W1 [128][512] f32 -> fp16, MFMA-B-fragment-linear ----------------
// element ((nt*4 + ks)*64 + lane)*8 + j  holds  W1[ks*32 + (lane>>4)*8 + j][nt*16 + (lane&15)]
__global__ void swizzle_w1(const float* __restrict__ W1, _Float16* __restrict__ dst) {
    int tid = blockIdx.x * blockDim.x + threadIdx.x;   // 0..65535
    int j    = tid & 7;
    int lane = (tid >> 3) & 63;
    int ks   = (tid >> 9) & 3;
    int nt   = tid >> 11;
    int k = ks * 32 + (lane >> 4) * 8 + j;
    int n = nt * 16 + (lane & 15);
    dst[tid] = (_Float16)W1[k * FH + n];
}

__device__ __forceinline__ float tanh_fast(float x) {
    x = fminf(fmaxf(x, -15.0f), 15.0f);   // compiles to v_med3_f32
    float e = __expf(x + x);
    return (e - 1.0f) * __builtin_amdgcn_rcpf(e + 1.0f);
}

__device__ __forceinline__ f32x4 mfma16(half8 a, half8 b, f32x4 c) {
    return __builtin_amdgcn_mfma_f32_16x16x32_f16(a, b, c, 0, 0, 0);
}

// USE_WS=1: W1 fragments loaded straight from global pre-swizzled workspace (L2-resident).
// Compute is a ROLLED loop over m-tiles (code must stay I$-resident: ~3 KB body, not 60 KB
// of unrolled straight-line code — the round-1 kernel was instruction-fetch bound).
template<int USE_WS>
__global__ __launch_bounds__(256, USE_WS ? 4 : 1)
void mhan_main(const float* __restrict__ item, const int* __restrict__ mask,
               const float* __restrict__ pos, const float* __restrict__ W1,
               const float* __restrict__ W2, const _Float16* __restrict__ w1sw,
               float* __restrict__ out)
{
    __shared__ half8  w1s_lds[USE_WS ? 1 : (NTILES * 4 * 64)];  // 131072 B only in fallback
    __shared__ float4 w2s[FH];                // 8192 B
    __shared__ float  attw[208 * NHD];        // 3328 B

    int tid = threadIdx.x;
    int b   = blockIdx.x;
    int lane = tid & 63, wave = tid >> 6;
    int q = lane >> 4, c = lane & 15;

    // ---- layout probe: 2 exact MFMAs reveal each C element's true (row,col) source slots ----
    int rowslot[4], colslot[4];
    {
        half8 pc_, pone;
#pragma unroll
        for (int j = 0; j < 8; ++j) { pc_[j] = (_Float16)(float)c; pone[j] = (_Float16)0.03125f; }
        f32x4 z = {0.f,0.f,0.f,0.f};
        f32x4 pr = mfma16(pc_, pone, z);   // value = source A-slot (row provenance)
        f32x4 pcv = mfma16(pone, pc_, z);  // value = source B-slot (col provenance)
#pragma unroll
        for (int r = 0; r < 4; ++r) {
            int rv = (int)(pr[r] + 0.5f);
            int cv = (int)(pcv[r] + 0.5f);
            rowslot[r] = rv < 0 ? 0 : (rv > 15 ? 15 : rv);
            colslot[r] = cv < 0 ? 0 : (cv > 15 ? 15 : cv);
        }
    }
    int okA = 1, okB = 1;
#pragma unroll
    for (int r = 0; r < 4; ++r) {
        okA &= (rowslot[r] == q * 4 + r) & (colslot[r] == c);
        okB &= (rowslot[r] == c) & (colslot[r] == q * 4 + r);
    }
    int path = __all(okA) ? 0 : (__all(okB) ? 1 : 2);

    // ---- stage W2, zero att; (fallback only: stage W1 into LDS) ----
    if constexpr (!USE_WS) {
        _Float16* w1f = (_Float16*)w1s_lds;
        for (int idx = tid; idx < HH * FH; idx += 256) {
            int j = idx & 7; int ln = (idx >> 3) & 63;
            int ks = (idx >> 9) & 3; int nt = idx >> 11;
            int k = ks * 32 + (ln >> 4) * 8 + j;
            int n = nt * 16 + (ln & 15);
            w1f[idx] = (_Float16)W1[k * FH + n];
        }
    }
    for (int i = tid; i < FH; i += 256) w2s[i] = ((const float4*)W2)[i];
    for (int i = tid; i < 208 * NHD; i += 256) attw[i] = 0.0f;
    __syncthreads();

    const half8* w1p;
    if constexpr (USE_WS) w1p = (const half8*)w1sw;
    else                  w1p = w1s_lds;

    const float* xb = item + (size_t)b * SS * HH;
    int nt0 = wave * 8;

    // ================= rolled m-tile loop (keep body compact & I$-resident) =================
#pragma unroll 1
    for (int mt = 0; mt < MTILES; ++mt) {
        // --- A fragments for this tile: x+pos -> fp16; slot c carries row mt*16 + c ---
        half8 af[4];
        int row = mt * 16 + c;
        bool ok = row < SS;
        const float4* xr = (const float4*)(xb + row * HH);
        const float4* pr = (const float4*)(pos + row * HH);
#pragma unroll
        for (int ks = 0; ks < 4; ++ks) {
            int ci = ks * 8 + q * 2;
            float4 x0, x1, p0, p1;
            if (ok) { x0 = xr[ci]; x1 = xr[ci + 1]; p0 = pr[ci]; p1 = pr[ci + 1]; }
            else {
                x0 = make_float4(0.f,0.f,0.f,0.f); x1 = x0; p0 = x0; p1 = x0;
            }
            half8 h;
            h[0] = (_Float16)(x0.x + p0.x); h[1] = (_Float16)(x0.y + p0.y);
            h[2] = (_Float16)(x0.z + p0.z); h[3] = (_Float16)(x0.w + p0.w);
            h[4] = (_Float16)(x1.x + p1.x); h[5] = (_Float16)(x1.y + p1.y);
            h[6] = (_Float16)(x1.z + p1.z); h[7] = (_Float16)(x1.w + p1.w);
            af[ks] = h;
        }

        float attp[4][NHD];
#pragma unroll
        for (int r = 0; r < 4; ++r)
#pragma unroll
            for (int k = 0; k < NHD; ++k) attp[r][k] = 0.0f;

        // --- nt loop in pairs: 2 independent MFMA chains + 2 in-flight B loads for ILP ---
#pragma unroll 1
        for (int nt = nt0; nt < nt0 + 8; nt += 2) {
            const half8* bp0 = &w1p[(nt * 4) * 64 + lane];
            const half8* bp1 = &w1p[((nt + 1) * 4) * 64 + lane];
            half8 bf0[4], bf1[4];
#pragma unroll
            for (int ks = 0; ks < 4; ++ks) { bf0[ks] = bp0[ks * 64]; bf1[ks] = bp1[ks * 64]; }
            f32x4 acc0 = {0.f,0.f,0.f,0.f}, acc1 = {0.f,0.f,0.f,0.f};
#pragma unroll
            for (int ks = 0; ks < 4; ++ks) {
                acc0 = mfma16(af[ks], bf0[ks], acc0);
                acc1 = mfma16(af[ks], bf1[ks], acc1);
            }
            // element r holds hidden[mt*16+rowslot[r]][nt*16+colslot[r]] (and nt+1)
#pragma unroll
            for (int r = 0; r < 4; ++r) {
                float4 w0 = w2s[nt * 16 + colslot[r]];
                float4 w1v = w2s[(nt + 1) * 16 + colslot[r]];
                float h0 = tanh_fast(acc0[r]);
                float h1 = tanh_fast(acc1[r]);
                attp[r][0] += h0 * w0.x + h1 * w1v.x;
                attp[r][1] += h0 * w0.y + h1 * w1v.y;
                attp[r][2] += h0 * w0.z + h1 * w1v.z;
                attp[r][3] += h0 * w0.w + h1 * w1v.w;
            }
        }

        // --- cross-lane reduce + LDS accumulate (4 waves share each row -> atomics) ---
        if (path == 0) {
            // guide map: rowslot[r]=q*4+r, colslot[r]=c — sum the 16 c-slots via xor 1,2,4,8
#pragma unroll
            for (int r = 0; r < 4; ++r)
#pragma unroll
                for (int k = 0; k < NHD; ++k) {
                    float v = attp[r][k];
                    v += __shfl_xor(v, 1);
                    v += __shfl_xor(v, 2);
                    v += __shfl_xor(v, 4);
                    v += __shfl_xor(v, 8);
                    if (c == 0)
                        atomicAdd(&attw[(mt * 16 + rowslot[r]) * NHD + k], v);
                }
        } else if (path == 1) {
            // swapped map: rowslot[r]=c, colslot[r]=q*4+r — sum r locally, xor 16,32 over q
#pragma unroll
            for (int k = 0; k < NHD; ++k) {
                float v = attp[0][k] + attp[1][k] + attp[2][k] + attp[3][k];
                v += __shfl_xor(v, 16);
                v += __shfl_xor(v, 32);
                if (q == 0)
                    atomicAdd(&attw[(mt * 16 + c) * NHD + k], v);
            }
        } else {
            // generic fallback: per-lane atomics, correct for any bijective map
#pragma unroll
            for (int r = 0; r < 4; ++r)
#pragma unroll
                for (int k = 0; k < NHD; ++k)
                    atomicAdd(&attw[(mt * 16 + rowslot[r]) * NHD + k], attp[r][k]);
        }
    }
    __syncthreads();

    // ---- masked softmax over S; head k = wave ----
    {
        int k = wave;
        float l[4];
        float m = -__builtin_inff();
#pragma unroll
        for (int i = 0; i < 4; ++i) {
            int s = lane + i * 64;
            if (s < SS) {
                float lv = (mask[(size_t)b * SS + s] != 0) ? attw[s * NHD + k] : NEGF;
                l[i] = lv;
                m = fmaxf(m, lv);
            } else {
                l[i] = -__builtin_inff();
            }
        }
#pragma unroll
        for (int off = 32; off >= 1; off >>= 1) m = fmaxf(m, __shfl_xor(m, off));
        float e[4], sum = 0.0f;
#pragma unroll
        for (int i = 0; i < 4; ++i) {
            e[i] = (l[i] == -__builtin_inff()) ? 0.0f : __expf(l[i] - m);
            sum += e[i];
        }
#pragma unroll
        for (int off = 32; off >= 1; off >>= 1) sum += __shfl_xor(sum, off);
        float inv = __builtin_amdgcn_rcpf(sum);
#pragma unroll
        for (int i = 0; i < 4; ++i) {
            int s = lane + i * 64;
            if (s < SS) attw[s * NHD + k] = e[i] * inv;
        }
    }
    // wave k wrote only column k; wave k reads only column k below — same-wave DS order suffices

    // ---- interest[k][h] = sum_s w[s,k] * x[s,h]  (fp32 out — reference output is float32) ----
    {
        int k = wave;
        float ax = 0.0f, ay = 0.0f;
#pragma unroll 8
        for (int s = 0; s < SS; ++s) {
            float w = attw[s * NHD + k];
            float2 xv = ((const float2*)(xb + s * HH))[lane];
            ax += w * xv.x;
            ay += w * xv.y;
        }
        size_t o = ((size_t)b * NHD + k) * HH + lane * 2;
        float2 ov; ov.x = ax; ov.y = ay;
        *(float2*)(out + o) = ov;
    }
}

extern "C" void kernel_launch(void* const* d_in, const int* in_sizes, int n_in,
                              void* d_out, int out_size, void* d_ws, size_t ws_size,
                              hipStream_t stream) {
    const float* item = (const float*)d_in[0];
    const int*   mask = (const int*)d_in[1];
    const float* pos  = (const float*)d_in[2];
    const float* W1   = (const float*)d_in[3];
    const float* W2   = (const float*)d_in[4];
    float* out = (float*)d_out;

    int B = in_sizes[0] / (SS * HH);
    int use_ws = (ws_size >= (size_t)(HH * FH * sizeof(_Float16))) ? 1 : 0;

    if (use_ws) {
        hipLaunchKernelGGL(swizzle_w1, dim3((HH * FH) / 256), dim3(256), 0, stream,
                           W1, (_Float16*)d_ws);
        mhan_main<1><<<dim3(B), dim3(256), 0, stream>>>(
            item, mask, pos, W1, W2, (const _Float16*)d_ws, out);
    } else {
        mhan_main<0><<<dim3(B), dim3(256), 0, stream>>>(
            item, mask, pos, W1, W2, (const _Float16*)nullptr, out);
    }
}

// Round 4
// 514.843 us; speedup vs baseline: 1.5740x; 1.1871x over previous
//
#include <hip/hip_runtime.h>
#include <hip/hip_bf16.h>

typedef _Float16 half8 __attribute__((ext_vector_type(8)));
typedef _Float16 half4 __attribute__((ext_vector_type(4)));
typedef float f32x4 __attribute__((ext_vector_type(4)));

#define SS 200
#define HH 128
#define NHD 4
#define FH 512
#define NTILES 32   // FH/16
#define MTILES 13   // ceil(SS/16)
#define RW 144      // fp16 row stride of staged x-tile (288 B: 16B-multiple, de-phases banks)
#define NEGF (-4294967295.0f)

// ---------------- pre-kernel: W1 [128][512] f32 -> fp16, MFMA-B-fragment-linear ----------------
// element ((nt*4 + ks)*64 + lane)*8 + j  holds  W1[ks*32 + (lane>>4)*8 + j][nt*16 + (lane&15)]
__global__ void swizzle_w1(const float* __restrict__ W1, _Float16* __restrict__ dst) {
    int tid = blockIdx.x * blockDim.x + threadIdx.x;   // 0..65535
    int j    = tid & 7;
    int lane = (tid >> 3) & 63;
    int ks   = (tid >> 9) & 3;
    int nt   = tid >> 11;
    int k = ks * 32 + (lane >> 4) * 8 + j;
    int n = nt * 16 + (lane & 15);
    dst[tid] = (_Float16)W1[k * FH + n];
}

__device__ __forceinline__ float tanh_fast(float x) {
    x = fminf(fmaxf(x, -15.0f), 15.0f);   // v_med3_f32
    float e = __expf(x + x);
    return (e - 1.0f) * __builtin_amdgcn_rcpf(e + 1.0f);
}

__device__ __forceinline__ f32x4 mfma16(half8 a, half8 b, f32x4 c) {
    return __builtin_amdgcn_mfma_f32_16x16x32_f16(a, b, c, 0, 0, 0);
}

// Round-4: round-2 passing base + ONE change: block-cooperative coalesced staging of
// (x+pos)->fp16 into a SINGLE LDS buffer, stage -> barrier -> compute -> barrier per tile.
// (Round-3's pipelined double-buffer + tail rewrite failed correctness; this localizes.)
template<int USE_WS>
__global__ __launch_bounds__(256, USE_WS ? 4 : 1)
void mhan_main(const float* __restrict__ item, const int* __restrict__ mask,
               const float* __restrict__ pos, const float* __restrict__ W1,
               const float* __restrict__ W2, const _Float16* __restrict__ w1sw,
               float* __restrict__ out)
{
    __shared__ __align__(16) _Float16 xs[16 * RW];      // 4608 B staged (x+pos) fp16, single buffer
    __shared__ float4 w2s[FH];                          // 8192 B
    __shared__ float  attw[208 * NHD];                  // 3328 B
    __shared__ half8  w1s_lds[USE_WS ? 1 : (NTILES * 4 * 64)];  // 128 KiB only in fallback

    int tid = threadIdx.x;
    int b   = blockIdx.x;
    int lane = tid & 63, wave = tid >> 6;
    int q = lane >> 4, c = lane & 15;

    // ---- layout probe: 2 exact MFMAs reveal each C element's true (row,col) source slots ----
    int rowslot[4], colslot[4];
    {
        half8 pc_, pone;
#pragma unroll
        for (int j = 0; j < 8; ++j) { pc_[j] = (_Float16)(float)c; pone[j] = (_Float16)0.03125f; }
        f32x4 z = {0.f,0.f,0.f,0.f};
        f32x4 pr = mfma16(pc_, pone, z);   // value = source A-slot (row provenance)
        f32x4 pcv = mfma16(pone, pc_, z);  // value = source B-slot (col provenance)
#pragma unroll
        for (int r = 0; r < 4; ++r) {
            int rv = (int)(pr[r] + 0.5f);
            int cv = (int)(pcv[r] + 0.5f);
            rowslot[r] = rv < 0 ? 0 : (rv > 15 ? 15 : rv);
            colslot[r] = cv < 0 ? 0 : (cv > 15 ? 15 : cv);
        }
    }
    int okA = 1, okB = 1;
#pragma unroll
    for (int r = 0; r < 4; ++r) {
        okA &= (rowslot[r] == q * 4 + r) & (colslot[r] == c);
        okB &= (rowslot[r] == c) & (colslot[r] == q * 4 + r);
    }
    int path = __all(okA) ? 0 : (__all(okB) ? 1 : 2);

    // ---- stage W2, zero att; (fallback only: stage W1 into LDS) ----
    if constexpr (!USE_WS) {
        _Float16* w1f = (_Float16*)w1s_lds;
        for (int idx = tid; idx < HH * FH; idx += 256) {
            int j = idx & 7; int ln = (idx >> 3) & 63;
            int ks = (idx >> 9) & 3; int nt = idx >> 11;
            int k = ks * 32 + (ln >> 4) * 8 + j;
            int n = nt * 16 + (ln & 15);
            w1f[idx] = (_Float16)W1[k * FH + n];
        }
    }
    for (int i = tid; i < FH; i += 256) w2s[i] = ((const float4*)W2)[i];
    for (int i = tid; i < 208 * NHD; i += 256) attw[i] = 0.0f;
    __syncthreads();

    const half8* w1p;
    if constexpr (USE_WS) w1p = (const half8*)w1sw;
    else                  w1p = w1s_lds;

    const float* xb = item + (size_t)b * SS * HH;
    int nt0 = wave * 8;

    // ================= m-tile loop: stage -> barrier -> compute -> barrier =================
#pragma unroll 1
    for (int mt = 0; mt < MTILES; ++mt) {
        // --- stage tile mt: coalesced block-cooperative (x+pos)->fp16 ---
#pragma unroll
        for (int i = 0; i < 2; ++i) {
            int u = tid + i * 256;             // 0..511 over 16 rows x 32 float4
            int row = u >> 5, col4 = u & 31;
            int grow = mt * 16 + row;
            float4 xv = make_float4(0.f,0.f,0.f,0.f), pv = xv;
            if (grow < SS) {
                xv = ((const float4*)(xb + grow * HH))[col4];
                pv = ((const float4*)(pos + grow * HH))[col4];
            }
            half4 h;
            h[0] = (_Float16)(xv.x + pv.x); h[1] = (_Float16)(xv.y + pv.y);
            h[2] = (_Float16)(xv.z + pv.z); h[3] = (_Float16)(xv.w + pv.w);
            *(half4*)&xs[row * RW + col4 * 4] = h;
        }
        __syncthreads();   // staged tile visible to all waves

        // --- A fragments straight from LDS (4x ds_read_b128) ---
        half8 af[4];
        {
            const _Float16* xp = &xs[c * RW + q * 8];
#pragma unroll
            for (int ks = 0; ks < 4; ++ks) af[ks] = *(const half8*)(xp + ks * 32);
        }

        float attp[4][NHD];
#pragma unroll
        for (int r = 0; r < 4; ++r)
#pragma unroll
            for (int k = 0; k < NHD; ++k) attp[r][k] = 0.0f;

        // --- nt loop in pairs: 2 independent MFMA chains + 2 in-flight B loads for ILP ---
#pragma unroll 1
        for (int nt = nt0; nt < nt0 + 8; nt += 2) {
            const half8* bp0 = &w1p[(nt * 4) * 64 + lane];
            const half8* bp1 = &w1p[((nt + 1) * 4) * 64 + lane];
            half8 bf0[4], bf1[4];
#pragma unroll
            for (int ks = 0; ks < 4; ++ks) { bf0[ks] = bp0[ks * 64]; bf1[ks] = bp1[ks * 64]; }
            f32x4 acc0 = {0.f,0.f,0.f,0.f}, acc1 = {0.f,0.f,0.f,0.f};
#pragma unroll
            for (int ks = 0; ks < 4; ++ks) {
                acc0 = mfma16(af[ks], bf0[ks], acc0);
                acc1 = mfma16(af[ks], bf1[ks], acc1);
            }
#pragma unroll
            for (int r = 0; r < 4; ++r) {
                float4 w0 = w2s[nt * 16 + colslot[r]];
                float4 w1v = w2s[(nt + 1) * 16 + colslot[r]];
                float h0 = tanh_fast(acc0[r]);
                float h1 = tanh_fast(acc1[r]);
                attp[r][0] += h0 * w0.x + h1 * w1v.x;
                attp[r][1] += h0 * w0.y + h1 * w1v.y;
                attp[r][2] += h0 * w0.z + h1 * w1v.z;
                attp[r][3] += h0 * w0.w + h1 * w1v.w;
            }
        }

        // --- cross-lane reduce + LDS accumulate ---
        if (path == 0) {
#pragma unroll
            for (int r = 0; r < 4; ++r)
#pragma unroll
                for (int k = 0; k < NHD; ++k) {
                    float v = attp[r][k];
                    v += __shfl_xor(v, 1);
                    v += __shfl_xor(v, 2);
                    v += __shfl_xor(v, 4);
                    v += __shfl_xor(v, 8);
                    if (c == 0)
                        atomicAdd(&attw[(mt * 16 + rowslot[r]) * NHD + k], v);
                }
        } else if (path == 1) {
#pragma unroll
            for (int k = 0; k < NHD; ++k) {
                float v = attp[0][k] + attp[1][k] + attp[2][k] + attp[3][k];
                v += __shfl_xor(v, 16);
                v += __shfl_xor(v, 32);
                if (q == 0)
                    atomicAdd(&attw[(mt * 16 + c) * NHD + k], v);
            }
        } else {
#pragma unroll
            for (int r = 0; r < 4; ++r)
#pragma unroll
                for (int k = 0; k < NHD; ++k)
                    atomicAdd(&attw[(mt * 16 + rowslot[r]) * NHD + k], attp[r][k]);
        }
        __syncthreads();   // af reads done before next tile's staging overwrites xs
    }
    // attw atomics all complete (loop-final barrier)

    // ---- masked softmax over S; head k = wave ----
    {
        int k = wave;
        float l[4];
        float m = -__builtin_inff();
#pragma unroll
        for (int i = 0; i < 4; ++i) {
            int s = lane + i * 64;
            if (s < SS) {
                float lv = (mask[(size_t)b * SS + s] != 0) ? attw[s * NHD + k] : NEGF;
                l[i] = lv;
                m = fmaxf(m, lv);
            } else {
                l[i] = -__builtin_inff();
            }
        }
#pragma unroll
        for (int off = 32; off >= 1; off >>= 1) m = fmaxf(m, __shfl_xor(m, off));
        float e[4], sum = 0.0f;
#pragma unroll
        for (int i = 0; i < 4; ++i) {
            e[i] = (l[i] == -__builtin_inff()) ? 0.0f : __expf(l[i] - m);
            sum += e[i];
        }
#pragma unroll
        for (int off = 32; off >= 1; off >>= 1) sum += __shfl_xor(sum, off);
        float inv = __builtin_amdgcn_rcpf(sum);
#pragma unroll
        for (int i = 0; i < 4; ++i) {
            int s = lane + i * 64;
            if (s < SS) attw[s * NHD + k] = e[i] * inv;
        }
    }
    // wave k wrote only column k; wave k reads only column k below — same-wave DS order suffices

    // ---- interest[k][h] = sum_s w[s,k] * x[s,h]  (fp32 out — reference output is float32) ----
    {
        int k = wave;
        float ax = 0.0f, ay = 0.0f;
#pragma unroll 8
        for (int s = 0; s < SS; ++s) {
            float w = attw[s * NHD + k];
            float2 xv = ((const float2*)(xb + s * HH))[lane];
            ax += w * xv.x;
            ay += w * xv.y;
        }
        size_t o = ((size_t)b * NHD + k) * HH + lane * 2;
        float2 ov; ov.x = ax; ov.y = ay;
        *(float2*)(out + o) = ov;
    }
}

extern "C" void kernel_launch(void* const* d_in, const int* in_sizes, int n_in,
                              void* d_out, int out_size, void* d_ws, size_t ws_size,
                              hipStream_t stream) {
    const float* item = (const float*)d_in[0];
    const int*   mask = (const int*)d_in[1];
    const float* pos  = (const float*)d_in[2];
    const float* W1   = (const float*)d_in[3];
    const float* W2   = (const float*)d_in[4];
    float* out = (float*)d_out;

    int B = in_sizes[0] / (SS * HH);
    int use_ws = (ws_size >= (size_t)(HH * FH * sizeof(_Float16))) ? 1 : 0;

    if (use_ws) {
        hipLaunchKernelGGL(swizzle_w1, dim3((HH * FH) / 256), dim3(256), 0, stream,
                           W1, (_Float16*)d_ws);
        mhan_main<1><<<dim3(B), dim3(256), 0, stream>>>(
            item, mask, pos, W1, W2, (const _Float16*)d_ws, out);
    } else {
        mhan_main<0><<<dim3(B), dim3(256), 0, stream>>>(
            item, mask, pos, W1, W2, (const _Float16*)nullptr, out);
    }
}